// Round 9
// baseline (170.406 us; speedup 1.0000x reference)
//
#include <hip/hip_runtime.h>
#include <hip/hip_bf16.h>

using short8  = __attribute__((ext_vector_type(8))) short;
using ushort8 = __attribute__((ext_vector_type(8))) unsigned short;
using f32x4   = __attribute__((ext_vector_type(4))) float;

__device__ inline void gload_lds16(const void* g, void* lds) {
    __builtin_amdgcn_global_load_lds(
        (const __attribute__((address_space(1))) void*)g,
        (__attribute__((address_space(3))) void*)lds, 16, 0, 0);
}

// 16-lane reduction via DPP row_ror (pure VALU, no LDS pipe).
template <int CTRL>
__device__ inline float dpp_add(float x) {
    int v = __builtin_amdgcn_update_dpp(0, __float_as_int(x), CTRL, 0xf, 0xf, true);
    return x + __int_as_float(v);
}
__device__ inline float reduce16(float x) {
    x = dpp_add<0x121>(x);
    x = dpp_add<0x122>(x);
    x = dpp_add<0x124>(x);
    x = dpp_add<0x128>(x);
    return x;
}

// Kernel 0: suffix-sum table ST[k][j] = sum_{q>=k} E[j][q].
__global__ __launch_bounds__(256) void suffix_kernel(const float* __restrict__ E,
                                                     float* __restrict__ ST, int m) {
    int j = blockIdx.x;
    int k = threadIdx.x;
    int lane = k & 63, w = k >> 6;
    __shared__ float wtot[4];
    float v = (k < m) ? E[(size_t)j * m + k] : 0.f;
    #pragma unroll
    for (int off = 1; off < 64; off <<= 1) {
        float o = __shfl_down(v, off);
        if (lane + off < 64) v += o;
    }
    if (lane == 0) wtot[w] = v;
    __syncthreads();
    float add = 0.f;
    #pragma unroll
    for (int w2 = 0; w2 < 4; ++w2)
        if (w2 > w) add += wtot[w2];
    v += add;
    if (k < m) ST[(size_t)k * m + j] = v;
}

// Kernel 1: per-row prep. 16 lanes per row (4 rows/wave). Assumes m == 256, B % 16 == 0.
__global__ __launch_bounds__(256) void prep_kernel(
    const float* __restrict__ z, const float* __restrict__ t,
    const float* __restrict__ e, const float* __restrict__ log_tau,
    const float* __restrict__ E, const float* __restrict__ L,
    const float* __restrict__ ST,
    __hip_bfloat16* __restrict__ hz, __hip_bfloat16* __restrict__ hy,
    float* __restrict__ g, float* __restrict__ acc, int B, int m)
{
    const int tid = threadIdx.x;
    const int row = blockIdx.x * 16 + (tid >> 4);
    const int sub = tid & 15;

    float tv = t[row], ev = e[row];

    int lo = 0, hi = m;
    while (lo < hi) { int mid = (lo + hi) >> 1; if (L[mid] < tv) lo = mid + 1; else hi = mid; }
    int idx = lo;
    if (idx == 0) idx = 1;
    if (idx == m) idx = m - 1;

    float Llo = L[idx - 1], Lhi = L[idx];
    float w    = (tv - Llo) / (Lhi - Llo);
    float invd = 1.0f / (float)(m - idx);
    float invtau = expf(-0.5f * log_tau[0]);

    const int j0 = sub * 16;
    f32x4 zv[4], El4[4], Eh4[4], Sc4[4], yv[4];
    #pragma unroll
    for (int q = 0; q < 4; ++q) {
        zv[q]  = *(const f32x4*)&z [(size_t)row * m + j0 + q * 4];
        El4[q] = *(const f32x4*)&E [(size_t)(idx - 1) * m + j0 + q * 4];
        Eh4[q] = *(const f32x4*)&E [(size_t)idx * m + j0 + q * 4];
        Sc4[q] = *(const f32x4*)&ST[(size_t)idx * m + j0 + q * 4];
    }
    float ssy = 0.f, ssz = 0.f;
    #pragma unroll
    for (int q = 0; q < 4; ++q)
        #pragma unroll
        for (int p = 0; p < 4; ++p) {
            float yint = El4[q][p] + (Eh4[q][p] - El4[q][p]) * w;
            float ycen = Sc4[q][p] * invd;
            float y = yint * ev + ycen * (1.f - ev);
            yv[q][p] = y; ssy += y * y;
            ssz += zv[q][p] * zv[q][p];
        }
    ssy = reduce16(ssy);
    ssz = reduce16(ssz);
    float sy = invtau / fmaxf(sqrtf(ssy), 1e-12f);
    float sz = invtau / fmaxf(sqrtf(ssz), 1e-12f);

    float gp = 0.f;
    ushort8 oy[2], oz[2];
    #pragma unroll
    for (int q = 0; q < 4; ++q)
        #pragma unroll
        for (int p = 0; p < 4; ++p) {
            float hyv = yv[q][p] * sy, hzv = zv[q][p] * sz;
            gp += hyv * hzv;
            __hip_bfloat16 hb = __float2bfloat16(hyv);
            __hip_bfloat16 zb = __float2bfloat16(hzv);
            oy[q >> 1][(q & 1) * 4 + p] = *reinterpret_cast<unsigned short*>(&hb);
            oz[q >> 1][(q & 1) * 4 + p] = *reinterpret_cast<unsigned short*>(&zb);
        }
    *(ushort8*)&hy[(size_t)row * m + j0]     = oy[0];
    *(ushort8*)&hy[(size_t)row * m + j0 + 8] = oy[1];
    *(ushort8*)&hz[(size_t)row * m + j0]     = oz[0];
    *(ushort8*)&hz[(size_t)row * m + j0 + 8] = oz[1];
    gp = reduce16(gp);
    if (sub == 0) { g[row] = gp; acc[row] = 0.f; }
}

// Kernel 2: fused sim = hz @ hy^T + exp + row partial sums.
// 128x128 tile, 4 waves (2x2, per-wave 64x64), BK=32, K=256 -> 8 K-tiles.
// Ring-3 LDS (3 x 8KB per operand = 48KB) -> 3 blocks/CU (cross-block overlap
// is the latency-hiding mechanism; barrier stalls of one block hide under the
// other blocks' MFMA). Depth-2 counted prefetch, steady vmcnt(4), never drained
// mid-loop. Swizzle f(r)=(r&3)^((r>>2)&3) on both source and read (rule 21).
__global__ __launch_bounds__(256, 3) void gemm_lse_kernel(
    const __hip_bfloat16* __restrict__ hz, const __hip_bfloat16* __restrict__ hy,
    float* __restrict__ row_acc, int Brows, int K)
{
    __shared__ __hip_bfloat16 As[3][128 * 32];
    __shared__ __hip_bfloat16 Bs[3][128 * 32];

    const int tid  = threadIdx.x;
    const int wid  = tid >> 6;   // 0..3
    const int lane = tid & 63;
    const int wm   = wid >> 1;   // 0..1
    const int wn   = wid & 1;    // 0..1
    const int lm   = lane & 15, lk = lane >> 4;

    // XCD swizzle (grid 64x64 = 4096, bijective): XCD k owns by-rows [8k, 8k+8),
    // bx fast -> each XCD streams full hy once (4MB, L2-resident) then hits L2 x7.
    int bx = blockIdx.x, by = blockIdx.y;
    if (gridDim.x == 64 && gridDim.y == 64) {
        int orig = by * 64 + bx;
        int xcd = orig & 7, pos = orig >> 3;   // pos in [0, 512)
        by = xcd * 8 + (pos >> 6);
        bx = pos & 63;
    }
    const int row0 = by * 128, col0 = bx * 128;

    f32x4 acc[4][4];
    #pragma unroll
    for (int i = 0; i < 4; ++i)
        #pragma unroll
        for (int j = 0; j < 4; ++j)
            acc[i][j] = (f32x4){0.f, 0.f, 0.f, 0.f};

#define FXOR(r) ((((r) & 3)) ^ (((r) >> 2) & 3))

    // Staging: tile = 128 rows x 32 k x 2B = 8KB = 512 x 16B chunks; 256 threads
    // cover C0 = tid (rows 0..63) and C1 = 256 + tid (rows 64..127).
    // LDS dest linear at chunk C; global source chunk q = (C&3) ^ f(r).
    const int r0s = tid >> 2;
    const int q0  = (tid & 3) ^ FXOR(r0s);
    const int r1s = 64 + (tid >> 2);
    const int q1  = (tid & 3) ^ FXOR(r1s);
    const int ldsc0 = (wid * 64) * 8;          // elem offset, load 0
    const int ldsc1 = (256 + wid * 64) * 8;    // elem offset, load 1

#define STAGE(SB, kt)                                                             \
    do {                                                                          \
        gload_lds16(hz + (size_t)(row0 + r0s) * 256 + (kt) * 32 + q0 * 8,         \
                    (void*)&As[SB][ldsc0]);                                       \
        gload_lds16(hz + (size_t)(row0 + r1s) * 256 + (kt) * 32 + q1 * 8,         \
                    (void*)&As[SB][ldsc1]);                                       \
        gload_lds16(hy + (size_t)(col0 + r0s) * 256 + (kt) * 32 + q0 * 8,         \
                    (void*)&Bs[SB][ldsc0]);                                       \
        gload_lds16(hy + (size_t)(col0 + r1s) * 256 + (kt) * 32 + q1 * 8,         \
                    (void*)&Bs[SB][ldsc1]);                                       \
    } while (0)

    short8 a[4], b[4];
#define RD(BUF)                                                                   \
    { _Pragma("unroll")                                                           \
      for (int mi = 0; mi < 4; ++mi) {                                            \
          int rt = wm * 64 + mi * 16 + lm;                                        \
          a[mi] = *(const short8*)&As[BUF][rt * 32 + ((lk ^ FXOR(rt)) << 3)];     \
      }                                                                           \
      _Pragma("unroll")                                                           \
      for (int ni = 0; ni < 4; ++ni) {                                            \
          int rt = wn * 64 + ni * 16 + lm;                                        \
          b[ni] = *(const short8*)&Bs[BUF][rt * 32 + ((lk ^ FXOR(rt)) << 3)];     \
      } }
#define MM                                                                        \
    { __builtin_amdgcn_s_setprio(1);                                              \
      _Pragma("unroll")                                                           \
      for (int mi = 0; mi < 4; ++mi)                                              \
          _Pragma("unroll")                                                       \
          for (int ni = 0; ni < 4; ++ni)                                          \
              acc[mi][ni] = __builtin_amdgcn_mfma_f32_16x16x32_bf16(              \
                  a[mi], b[ni], acc[mi][ni], 0, 0, 0);                            \
      __builtin_amdgcn_s_setprio(0); }

#define BAR do { asm volatile("" ::: "memory"); __builtin_amdgcn_s_barrier();     \
                 asm volatile("" ::: "memory"); } while (0)
#define WAITV(N) asm volatile("s_waitcnt vmcnt(" N ")" ::: "memory")

    // Tile T (slot T%3): RD(T); STAGE(T+2) into slot (T+2)%3 = (T-1)%3 -- safe:
    // reads of T-1 retired at MM(T-1)'s lgkm wait, before the barrier we passed.
    // WAITV retires oldest 4 loads = tile T+1's -> gate for next iteration.
#define TILE(T, SLOT, DO_STAGE, NSLOT, WS)                                        \
    {                                                                             \
        RD(SLOT)                                                                  \
        if (DO_STAGE) STAGE(NSLOT, (T) + 2);                                      \
        WAITV(WS);                                                                \
        BAR;                                                                      \
        MM                                                                        \
        BAR;                                                                      \
    }

    // prologue: prime tiles 0 (slot0) and 1 (slot1); gate tile 0.
    STAGE(0, 0);
    STAGE(1, 1);
    WAITV("4");
    BAR;

    TILE(0, 0, 1, 2, "4")
    TILE(1, 1, 1, 0, "4")
    TILE(2, 2, 1, 1, "4")
    TILE(3, 0, 1, 2, "4")
    TILE(4, 1, 1, 0, "4")
    TILE(5, 2, 1, 1, "4")
    TILE(6, 0, 0, 0, "0")
    TILE(7, 1, 0, 0, "0")

#undef TILE
#undef STAGE
#undef RD
#undef MM
#undef BAR
#undef WAITV
#undef FXOR

    // Epilogue: exp + row sums (DPP reduce). C/D: col = lane&15, row = (lane>>4)*4 + reg.
    const int lg = lane >> 4;
    #pragma unroll
    for (int mi = 0; mi < 4; ++mi) {
        float rs[4] = {0.f, 0.f, 0.f, 0.f};
        #pragma unroll
        for (int ni = 0; ni < 4; ++ni) {
            #pragma unroll
            for (int r = 0; r < 4; ++r) rs[r] += __expf(acc[mi][ni][r]);
        }
        #pragma unroll
        for (int r = 0; r < 4; ++r) {
            float s = reduce16(rs[r]);
            if (lm == 0)
                unsafeAtomicAdd(&row_acc[row0 + wm * 64 + mi * 16 + lg * 4 + r], s);
        }
    }
}

// Kernel 3: out = clip(log(acc) - g - log(B), -5, 15)
__global__ void finalize_kernel(const float* __restrict__ acc, const float* __restrict__ g,
                                float* __restrict__ out, int B) {
    int i = blockIdx.x * 256 + threadIdx.x;
    if (i < B) {
        float v = logf(acc[i]) - g[i] - logf((float)B);
        out[i] = fminf(fmaxf(v, -5.f), 15.f);
    }
}

extern "C" void kernel_launch(void* const* d_in, const int* in_sizes, int n_in,
                              void* d_out, int out_size, void* d_ws, size_t ws_size,
                              hipStream_t stream) {
    const float* z       = (const float*)d_in[0];
    const float* t       = (const float*)d_in[1];
    const float* e       = (const float*)d_in[2];
    const float* log_tau = (const float*)d_in[3];
    const float* E       = (const float*)d_in[4];
    const float* L       = (const float*)d_in[5];
    float* out = (float*)d_out;

    const int B = in_sizes[1];   // 8192
    const int m = in_sizes[5];   // 256

    char* w = (char*)d_ws;
    __hip_bfloat16* hz = (__hip_bfloat16*)w;                 // B*m bf16
    __hip_bfloat16* hy = hz + (size_t)B * m;                 // B*m bf16
    float* ST   = (float*)(hy + (size_t)B * m);              // m*m f32
    float* g    = ST + (size_t)m * m;                        // B f32
    float* acc  = g + B;                                     // B f32

    suffix_kernel<<<m, 256, 0, stream>>>(E, ST, m);
    prep_kernel<<<B / 16, 256, 0, stream>>>(z, t, e, log_tau, E, L, ST, hz, hy, g, acc, B, m);
    dim3 grid2(64, 64);
    gemm_lse_kernel<<<grid2, 256, 0, stream>>>(hz, hy, acc, B, m);
    finalize_kernel<<<(B + 255) / 256, 256, 0, stream>>>(acc, g, out, B);
}

// Round 10
// 117.009 us; speedup vs baseline: 1.4563x; 1.4563x over previous
//
#include <hip/hip_runtime.h>
#include <hip/hip_bf16.h>

using short8  = __attribute__((ext_vector_type(8))) short;
using ushort8 = __attribute__((ext_vector_type(8))) unsigned short;
using f32x4   = __attribute__((ext_vector_type(4))) float;

__device__ inline void gload_lds16(const void* g, void* lds) {
    __builtin_amdgcn_global_load_lds(
        (const __attribute__((address_space(1))) void*)g,
        (__attribute__((address_space(3))) void*)lds, 16, 0, 0);
}

// 16-lane reduction via DPP row_ror (pure VALU, no LDS pipe).
template <int CTRL>
__device__ inline float dpp_add(float x) {
    int v = __builtin_amdgcn_update_dpp(0, __float_as_int(x), CTRL, 0xf, 0xf, true);
    return x + __int_as_float(v);
}
__device__ inline float reduce16(float x) {
    x = dpp_add<0x121>(x);
    x = dpp_add<0x122>(x);
    x = dpp_add<0x124>(x);
    x = dpp_add<0x128>(x);
    return x;
}

// Kernel 0: suffix-sum table ST[k][j] = sum_{q>=k} E[j][q].
__global__ __launch_bounds__(256) void suffix_kernel(const float* __restrict__ E,
                                                     float* __restrict__ ST, int m) {
    int j = blockIdx.x;
    int k = threadIdx.x;
    int lane = k & 63, w = k >> 6;
    __shared__ float wtot[4];
    float v = (k < m) ? E[(size_t)j * m + k] : 0.f;
    #pragma unroll
    for (int off = 1; off < 64; off <<= 1) {
        float o = __shfl_down(v, off);
        if (lane + off < 64) v += o;
    }
    if (lane == 0) wtot[w] = v;
    __syncthreads();
    float add = 0.f;
    #pragma unroll
    for (int w2 = 0; w2 < 4; ++w2)
        if (w2 > w) add += wtot[w2];
    v += add;
    if (k < m) ST[(size_t)k * m + j] = v;
}

// Kernel 1: per-row prep. 16 lanes per row (4 rows/wave). Assumes m == 256, B % 16 == 0.
__global__ __launch_bounds__(256) void prep_kernel(
    const float* __restrict__ z, const float* __restrict__ t,
    const float* __restrict__ e, const float* __restrict__ log_tau,
    const float* __restrict__ E, const float* __restrict__ L,
    const float* __restrict__ ST,
    __hip_bfloat16* __restrict__ hz, __hip_bfloat16* __restrict__ hy,
    float* __restrict__ g, float* __restrict__ acc, int B, int m)
{
    const int tid = threadIdx.x;
    const int row = blockIdx.x * 16 + (tid >> 4);
    const int sub = tid & 15;

    float tv = t[row], ev = e[row];

    int lo = 0, hi = m;
    while (lo < hi) { int mid = (lo + hi) >> 1; if (L[mid] < tv) lo = mid + 1; else hi = mid; }
    int idx = lo;
    if (idx == 0) idx = 1;
    if (idx == m) idx = m - 1;

    float Llo = L[idx - 1], Lhi = L[idx];
    float w    = (tv - Llo) / (Lhi - Llo);
    float invd = 1.0f / (float)(m - idx);
    float invtau = expf(-0.5f * log_tau[0]);

    const int j0 = sub * 16;
    f32x4 zv[4], El4[4], Eh4[4], Sc4[4], yv[4];
    #pragma unroll
    for (int q = 0; q < 4; ++q) {
        zv[q]  = *(const f32x4*)&z [(size_t)row * m + j0 + q * 4];
        El4[q] = *(const f32x4*)&E [(size_t)(idx - 1) * m + j0 + q * 4];
        Eh4[q] = *(const f32x4*)&E [(size_t)idx * m + j0 + q * 4];
        Sc4[q] = *(const f32x4*)&ST[(size_t)idx * m + j0 + q * 4];
    }
    float ssy = 0.f, ssz = 0.f;
    #pragma unroll
    for (int q = 0; q < 4; ++q)
        #pragma unroll
        for (int p = 0; p < 4; ++p) {
            float yint = El4[q][p] + (Eh4[q][p] - El4[q][p]) * w;
            float ycen = Sc4[q][p] * invd;
            float y = yint * ev + ycen * (1.f - ev);
            yv[q][p] = y; ssy += y * y;
            ssz += zv[q][p] * zv[q][p];
        }
    ssy = reduce16(ssy);
    ssz = reduce16(ssz);
    float sy = invtau / fmaxf(sqrtf(ssy), 1e-12f);
    float sz = invtau / fmaxf(sqrtf(ssz), 1e-12f);

    float gp = 0.f;
    ushort8 oy[2], oz[2];
    #pragma unroll
    for (int q = 0; q < 4; ++q)
        #pragma unroll
        for (int p = 0; p < 4; ++p) {
            float hyv = yv[q][p] * sy, hzv = zv[q][p] * sz;
            gp += hyv * hzv;
            __hip_bfloat16 hb = __float2bfloat16(hyv);
            __hip_bfloat16 zb = __float2bfloat16(hzv);
            oy[q >> 1][(q & 1) * 4 + p] = *reinterpret_cast<unsigned short*>(&hb);
            oz[q >> 1][(q & 1) * 4 + p] = *reinterpret_cast<unsigned short*>(&zb);
        }
    *(ushort8*)&hy[(size_t)row * m + j0]     = oy[0];
    *(ushort8*)&hy[(size_t)row * m + j0 + 8] = oy[1];
    *(ushort8*)&hz[(size_t)row * m + j0]     = oz[0];
    *(ushort8*)&hz[(size_t)row * m + j0 + 8] = oz[1];
    gp = reduce16(gp);
    if (sub == 0) { g[row] = gp; acc[row] = 0.f; }
}

// Kernel 2: A-resident fused GEMM+LSE.
// 256 blocks = 32 row-panels x 8 col-groups. 512 threads (8 waves, 2M x 4N;
// per-wave 128 rows x 64 cols). A-panel (256 rows x K=256, 128 KB) staged ONCE,
// swizzled; B streams through a 2 x 16 KB ring (BK=32), 32 uniform phases
// (4 col-tiles x 8 K-steps). LDS = 160 KB exactly. Row-sums accumulate in
// registers across col-tiles; one atomic pass per block.
// Swizzles (rule 21: inverse-swizzled global source, linear LDS dest, swizzled read):
//   A: row r (512B), chunk c(0..31): LDS slot = c ^ (r&7)           -> min-conflict
//   B: row-pair p (128B), slot s(0..7) = ((r&1)*4 + q) ^ (p&7)      -> min-conflict
__global__ __launch_bounds__(512, 2) void gemm_lse_kernel(
    const __hip_bfloat16* __restrict__ hz, const __hip_bfloat16* __restrict__ hy,
    float* __restrict__ row_acc, int Brows, int K)
{
    __shared__ __hip_bfloat16 As[256 * 256];     // 128 KB
    __shared__ __hip_bfloat16 Bs[2][256 * 32];   // 32 KB

    const int tid  = threadIdx.x;
    const int wid  = tid >> 6;
    const int lane = tid & 63;
    const int wm   = wid >> 2;   // 0..1
    const int wn   = wid & 3;    // 0..3
    const int lm   = lane & 15, lk = lane >> 4;

    const int cg = blockIdx.x & 7;    // col-group (XCD-affine under round-robin)
    const int rp = blockIdx.x >> 3;   // row-panel
    const int row0 = rp * 256;
    const int colbase = cg * 4 * 256; // first col of this block's 4 col-tiles

#define BAR do { asm volatile("" ::: "memory"); __builtin_amdgcn_s_barrier();     \
                 asm volatile("" ::: "memory"); } while (0)
#define WAITV0 asm volatile("s_waitcnt vmcnt(0)" ::: "memory")

    // ---- Stage A panel (16 loads/thread). LDS chunk C: r=C>>5, slot u=C&31;
    // content = global chunk u^(r&7). ----
    #pragma unroll
    for (int s = 0; s < 16; ++s) {
        int C = wid * 1024 + s * 64 + lane;
        int r = C >> 5, u = C & 31;
        gload_lds16(hz + (size_t)(row0 + r) * 256 + ((u ^ (r & 7)) << 3),
                    (void*)&As[(wid * 1024 + s * 64) * 8]);
    }

    // ---- B staging: tile (ct,kt) -> buf. LDS chunk C(0..1023): p=C>>3, s3=C&7,
    // t = s3^(p&7); content = global row 2p+(t>>2), chunk t&3. 2 loads/thread. ----
#define STAGE_B(BUF, CT_, KT_)                                                    \
    { _Pragma("unroll")                                                           \
      for (int s = 0; s < 2; ++s) {                                               \
          int C = s * 512 + wid * 64 + lane;                                      \
          int p_ = C >> 3, t_ = (C & 7) ^ (p_ & 7);                               \
          gload_lds16(hy + (size_t)(colbase + (CT_) * 256 + 2 * p_ + (t_ >> 2)) * 256 \
                          + (KT_) * 32 + ((t_ & 3) << 3),                         \
                      (void*)&Bs[BUF][(s * 512 + wid * 64) * 8]);                 \
      } }

    // ---- fragment reads (swizzled) ----
#define RD_A(HALF, KT_)                                                           \
    { _Pragma("unroll")                                                           \
      for (int mi = 0; mi < 4; ++mi) {                                            \
          int rt = wm * 128 + (HALF) * 64 + mi * 16 + lm;                         \
          a[mi] = *(const short8*)&As[rt * 256 + ((((KT_) * 4 + lk) ^ (rt & 7)) << 3)]; \
      } }
#define RD_B(BUF)                                                                 \
    { _Pragma("unroll")                                                           \
      for (int ni = 0; ni < 4; ++ni) {                                            \
          int rt = wn * 64 + ni * 16 + lm;                                        \
          b[ni] = *(const short8*)&Bs[BUF][((rt >> 1) << 6) +                     \
                   (((((rt & 1) << 2) | lk) ^ ((rt >> 1) & 7)) << 3)];            \
      } }

    f32x4 acc[8][4];
    float rs[8][4];
    #pragma unroll
    for (int i = 0; i < 8; ++i)
        #pragma unroll
        for (int j = 0; j < 4; ++j) {
            acc[i][j] = (f32x4){0.f, 0.f, 0.f, 0.f};
            rs[i][j] = 0.f;
        }

    short8 a[4], b[4];

    // prologue: B(ct0,kt0) into buf 0; drain own loads; join.
    STAGE_B(0, 0, 0);
    WAITV0;
    BAR;

    for (int p = 0; p < 32; ++p) {
        const int kt = p & 7, buf = p & 1;

        RD_B(buf)
        RD_A(0, kt)
        if (p < 31) {
            const int pn = p + 1;
            STAGE_B(pn & 1, pn >> 3, pn & 7);   // buf (p+1)&1: its last reads were phase p-1
        }
        __builtin_amdgcn_s_setprio(1);
        #pragma unroll
        for (int mi = 0; mi < 4; ++mi)
            #pragma unroll
            for (int ni = 0; ni < 4; ++ni)
                acc[mi][ni] = __builtin_amdgcn_mfma_f32_16x16x32_bf16(
                    a[mi], b[ni], acc[mi][ni], 0, 0, 0);
        __builtin_amdgcn_s_setprio(0);
        RD_A(1, kt)
        __builtin_amdgcn_s_setprio(1);
        #pragma unroll
        for (int mi = 0; mi < 4; ++mi)
            #pragma unroll
            for (int ni = 0; ni < 4; ++ni)
                acc[4 + mi][ni] = __builtin_amdgcn_mfma_f32_16x16x32_bf16(
                    a[mi], b[ni], acc[4 + mi][ni], 0, 0, 0);
        __builtin_amdgcn_s_setprio(0);

        if (kt == 7) {
            // col-tile complete: exp-accumulate into rs, reset acc.
            #pragma unroll
            for (int mi = 0; mi < 8; ++mi)
                #pragma unroll
                for (int ni = 0; ni < 4; ++ni) {
                    #pragma unroll
                    for (int r = 0; r < 4; ++r)
                        rs[mi][r] += __expf(acc[mi][ni][r]);
                    acc[mi][ni] = (f32x4){0.f, 0.f, 0.f, 0.f};
                }
        }
        // gate: next phase reads buf (p+1)&1 staged this phase; own drain + join.
        WAITV0;
        BAR;
    }

#undef STAGE_B
#undef RD_A
#undef RD_B
#undef BAR
#undef WAITV0

    // Final: reduce row sums, one atomic pass. C/D: col=lane&15, row=(lane>>4)*4+reg.
    const int lg = lane >> 4;
    #pragma unroll
    for (int mi = 0; mi < 8; ++mi)
        #pragma unroll
        for (int r = 0; r < 4; ++r) {
            float s = reduce16(rs[mi][r]);
            if (lm == 0)
                unsafeAtomicAdd(&row_acc[row0 + wm * 128 + mi * 16 + lg * 4 + r], s);
        }
}

// Kernel 3: out = clip(log(acc) - g - log(B), -5, 15)
__global__ void finalize_kernel(const float* __restrict__ acc, const float* __restrict__ g,
                                float* __restrict__ out, int B) {
    int i = blockIdx.x * 256 + threadIdx.x;
    if (i < B) {
        float v = logf(acc[i]) - g[i] - logf((float)B);
        out[i] = fminf(fmaxf(v, -5.f), 15.f);
    }
}

extern "C" void kernel_launch(void* const* d_in, const int* in_sizes, int n_in,
                              void* d_out, int out_size, void* d_ws, size_t ws_size,
                              hipStream_t stream) {
    const float* z       = (const float*)d_in[0];
    const float* t       = (const float*)d_in[1];
    const float* e       = (const float*)d_in[2];
    const float* log_tau = (const float*)d_in[3];
    const float* E       = (const float*)d_in[4];
    const float* L       = (const float*)d_in[5];
    float* out = (float*)d_out;

    const int B = in_sizes[1];   // 8192
    const int m = in_sizes[5];   // 256

    char* w = (char*)d_ws;
    __hip_bfloat16* hz = (__hip_bfloat16*)w;                 // B*m bf16
    __hip_bfloat16* hy = hz + (size_t)B * m;                 // B*m bf16
    float* ST   = (float*)(hy + (size_t)B * m);              // m*m f32
    float* g    = ST + (size_t)m * m;                        // B f32
    float* acc  = g + B;                                     // B f32

    suffix_kernel<<<m, 256, 0, stream>>>(E, ST, m);
    prep_kernel<<<B / 16, 256, 0, stream>>>(z, t, e, log_tau, E, L, ST, hz, hy, g, acc, B, m);
    gemm_lse_kernel<<<256, 512, 0, stream>>>(hz, hy, acc, B, m);
    finalize_kernel<<<(B + 255) / 256, 256, 0, stream>>>(acc, g, out, B);
}